// Round 11
// baseline (1301.672 us; speedup 1.0000x reference)
//
#include <hip/hip_runtime.h>

#define NN   100000
#define EE   1600000
#define FDIM 128
#define NFAC 4
#define DD   64
#define NLAY 3
#define GG   128

// node state is deinterleaved per factor: [f][n][64] bf16, one 128B cacheline per (f,n)

// prep weight buffer layout (bf16 elems), per-factor stride:
#define PF_STRIDE 57344
#define OFF_WREL  8192
#define OFF_WROOT 20480
#define OFF_WIH   32768
#define OFF_WHH   45056
#define PREP_TOTAL (NFAC * PF_STRIDE)   // 229376

typedef __bf16 bf16x8_t __attribute__((ext_vector_type(8)));
typedef float  f32x4_t  __attribute__((ext_vector_type(4)));

__device__ __forceinline__ unsigned short f2bf(float x) {
    unsigned u = __float_as_uint(x);
    u += 0x7fffu + ((u >> 16) & 1u);        // round-to-nearest-even
    return (unsigned short)(u >> 16);
}
__device__ __forceinline__ float b2f(unsigned short h) {
    return __uint_as_float(((unsigned)h) << 16);
}
__device__ __forceinline__ float sigm(float x) { return 1.f / (1.f + __expf(-x)); }
__device__ __forceinline__ float tanh_f(float x) {
    float t = __expf(-2.f * fabsf(x));
    float r = (1.f - t) / (1.f + t);
    return x >= 0.f ? r : -r;
}

// ---------------------------------------------------------------- init
__global__ __launch_bounds__(256) void k_init(int* deg, int* cursor, float* outs, int* hist) {
    int i = blockIdx.x * 256 + threadIdx.x;
    if (i < NN) { deg[i] = 0; cursor[i] = 0; }
    if (i < NFAC * GG * DD) outs[i] = 0.f;
    if (i < 256) hist[i] = 0;
}

// ------------------------------------------------- weight + x bf16 prep
// B-fragment order: for matrix B[k][n]: elem((nt*KB+kb)*64+lane)*8+j = B[kb*32+(lane>>4)*8+j][nt*16+(lane&15)]
__global__ __launch_bounds__(256) void k_prep(const float* x, const float* linW,
                                              const float* wrel, const float* wroot,
                                              const float* wih, const float* whh,
                                              unsigned short* x16, unsigned short* prep) {
    for (int i = blockIdx.x * 256 + threadIdx.x; i < NN * FDIM; i += gridDim.x * 256)
        x16[i] = f2bf(x[i]);
    for (int idx = blockIdx.x * 256 + threadIdx.x; idx < PREP_TOTAL; idx += gridDim.x * 256) {
        int f = idx / PF_STRIDE, r = idx % PF_STRIDE;
        int e, KB, mode, l = 0;
        if (r < OFF_WREL)       { e = r;                 KB = 4; mode = 0; }
        else if (r < OFF_WROOT) { int rr = r - OFF_WREL;  l = rr >> 12; e = rr & 4095; KB = 2; mode = 1; }
        else if (r < OFF_WIH)   { int rr = r - OFF_WROOT; l = rr >> 12; e = rr & 4095; KB = 2; mode = 2; }
        else if (r < OFF_WHH)   { e = r - OFF_WIH;        KB = 2; mode = 3; }
        else                    { e = r - OFF_WHH;        KB = 2; mode = 4; }
        int j = e & 7, lane = (e >> 3) & 63, t = e >> 9;
        int kb = t % KB, nt = t / KB;
        int k = kb * 32 + (lane >> 4) * 8 + j;
        int n = nt * 16 + (lane & 15);
        float v;
        if (mode == 0)      v = linW[(f * FDIM + k) * DD + n];
        else if (mode == 1) v = wrel[((f * 3 + l) * DD + k) * DD + n];
        else if (mode == 2) v = wroot[((f * 3 + l) * DD + k) * DD + n];
        else if (mode == 3) v = wih[(f * 192 + n) * DD + k];   // B = Wih^T
        else                v = whh[(f * 192 + n) * DD + k];
        prep[idx] = f2bf(v);
    }
}

// ---------------------------------------------------------------- counts: batch sorted -> binary search, no atomics
__global__ __launch_bounds__(256) void k_count(const int* batch, float* counts) {
    __shared__ int lb[GG + 1];
    int t = threadIdx.x;
    if (t <= GG) {
        int lo = 0, hi = NN;
        while (lo < hi) { int mid = (lo + hi) >> 1; if (batch[mid] < t) lo = mid + 1; else hi = mid; }
        lb[t] = lo;
    }
    __syncthreads();
    if (t < GG) counts[t] = (float)(lb[t + 1] - lb[t]);
}

// ---------------------------------------------------------------- CSR build
__global__ __launch_bounds__(256) void k_deg(const int* ei, int* deg) {
    int e = blockIdx.x * 256 + threadIdx.x;
    if (e < EE) atomicAdd(&deg[ei[EE + e]], 1);
}
__global__ __launch_bounds__(256) void k_scan1(const int* deg, int* row_pos, int* bsum) {
    __shared__ int lds[256];
    int tid = threadIdx.x, idx = blockIdx.x * 256 + tid;
    int v = (idx < NN) ? deg[idx] : 0;
    lds[tid] = v; __syncthreads();
    for (int s = 1; s < 256; s <<= 1) {
        int t = (tid >= s) ? lds[tid - s] : 0;
        __syncthreads();
        lds[tid] += t;
        __syncthreads();
    }
    if (idx < NN) row_pos[idx] = lds[tid] - v;   // exclusive within block
    if (tid == 255) bsum[blockIdx.x] = lds[255];
}
__global__ __launch_bounds__(512) void k_scan2(int* bsum) {  // 1 block, 512 threads, 391 valid
    __shared__ int lds[512];
    int tid = threadIdx.x;
    int v = (tid < 391) ? bsum[tid] : 0;
    lds[tid] = v; __syncthreads();
    for (int s = 1; s < 512; s <<= 1) {
        int t = (tid >= s) ? lds[tid - s] : 0;
        __syncthreads();
        lds[tid] += t;
        __syncthreads();
    }
    bsum[tid] = lds[tid] - v;                    // exclusive block offsets
}
__global__ __launch_bounds__(256) void k_rowptr(const int* row_pos, const int* boff, int* row_ptr) {
    int i = blockIdx.x * 256 + threadIdx.x;
    if (i < NN) row_ptr[i] = row_pos[i] + boff[i >> 8];
    if (i == 0) row_ptr[NN] = EE;
}
__global__ __launch_bounds__(256) void k_fill(const int* ei, const float* att,
                                              const int* row_ptr, int* cursor,
                                              int* csr_src, float* csr_att) {
    int e = blockIdx.x * 256 + threadIdx.x;
    if (e >= EE) return;
    int d = ei[EE + e];
    int slot = row_ptr[d] + atomicAdd(&cursor[d], 1);
    csr_src[slot] = ei[e];
    *(float4*)(csr_att + (size_t)slot * 4) =
        make_float4(att[e], att[EE + e], att[2 * EE + e], att[3 * EE + e]);
}
// transpose csr_att [E][4] -> att_t [4][E]; coalesced read + 4 coalesced plane writes
__global__ __launch_bounds__(256) void k_att(const float* csr_att, float* att_t) {
    int e = blockIdx.x * 256 + threadIdx.x;
    if (e >= EE) return;
    float4 v = *(const float4*)(csr_att + (size_t)e * 4);
    att_t[e]                  = v.x;
    att_t[(size_t)EE + e]     = v.y;
    att_t[(size_t)2 * EE + e] = v.z;
    att_t[(size_t)3 * EE + e] = v.w;
}

// ---------------------------------------------------------------- degree counting-sort (for gather load balance)
__global__ __launch_bounds__(256) void k_hist(const int* deg, int* hist) {
    __shared__ int lh[256];
    int tid = threadIdx.x;
    lh[tid] = 0; __syncthreads();
    int i = blockIdx.x * 256 + tid;
    if (i < NN) { int b = deg[i]; if (b > 255) b = 255; atomicAdd(&lh[b], 1); }
    __syncthreads();
    if (lh[tid]) atomicAdd(&hist[tid], lh[tid]);
}
__global__ __launch_bounds__(256) void k_hscan(int* hist, int* hcur) {  // 1 block
    __shared__ int lds[256];
    int tid = threadIdx.x;
    int v = hist[tid];
    lds[tid] = v; __syncthreads();
    for (int s = 1; s < 256; s <<= 1) {
        int t = (tid >= s) ? lds[tid - s] : 0;
        __syncthreads();
        lds[tid] += t;
        __syncthreads();
    }
    hist[tid] = lds[tid] - v;                    // exclusive bin offsets
    hcur[tid] = 0;
}
__global__ __launch_bounds__(256) void k_perm(const int* deg, const int* hist, int* hcur, int* perm) {
    int i = blockIdx.x * 256 + threadIdx.x;
    if (i >= NN) return;
    int b = deg[i]; if (b > 255) b = 255;
    int pos = hist[b] + atomicAdd(&hcur[b], 1);
    perm[pos] = i;                               // nodes sorted by degree -> waves see equal trip counts
}

// ---------------------------------------------------------------- lin: wave = factor; b-frags loaded once per nt,
// a-frags preloaded to VGPR; writes deinterleaved out16 [f][n][64]
__global__ __launch_bounds__(256) void k_lin(const unsigned short* x16, const unsigned short* prep,
                                             const float* linb, unsigned short* out16) {
    int n0 = blockIdx.x * 64;
    __shared__ unsigned short xs[64 * 136];      // 128 cols + 8 pad
    int tid = threadIdx.x;
    for (int t = tid; t < 1024; t += 256) {      // 64 rows x 16 segs x 8 elems
        int row = t >> 4, seg = t & 15;
        int gn = n0 + row; if (gn >= NN) gn = NN - 1;
        *(uint4*)(xs + row * 136 + seg * 8) = *(const uint4*)(x16 + (size_t)gn * FDIM + seg * 8);
    }
    __syncthreads();
    int w = tid >> 6, lane = tid & 63, mrow = lane & 15, q = lane >> 4;
    const unsigned short* wp = prep + w * PF_STRIDE;
    bf16x8_t a[4][4];                            // [mt][kb], all row-tiles
#pragma unroll
    for (int mt = 0; mt < 4; mt++)
#pragma unroll
        for (int kb = 0; kb < 4; kb++)
            a[mt][kb] = *(const bf16x8_t*)(xs + (mt * 16 + mrow) * 136 + kb * 32 + q * 8);
#pragma unroll
    for (int nt = 0; nt < 4; nt++) {
        bf16x8_t b[4];
#pragma unroll
        for (int kb = 0; kb < 4; kb++)
            b[kb] = *(const bf16x8_t*)(wp + ((nt * 4 + kb) * 64 + lane) * 8);
        int col = nt * 16 + mrow;
        float bias = linb[w * DD + col];
#pragma unroll
        for (int mt = 0; mt < 4; mt++) {
            f32x4_t acc = {0.f, 0.f, 0.f, 0.f};
#pragma unroll
            for (int kb = 0; kb < 4; kb++)
                acc = __builtin_amdgcn_mfma_f32_16x16x32_bf16(a[mt][kb], b[kb], acc, 0, 0, 0);
#pragma unroll
            for (int r = 0; r < 4; r++) {
                int node = n0 + mt * 16 + q * 4 + r;
                if (node < NN) out16[((size_t)w * NN + node) * DD + col] = f2bf(acc[r] + bias);
            }
        }
    }
}

// ---------------------------------------------------------------- gather (R6 form + degree-sorted order):
// per-factor passes (blockIdx.y = f); 16-lane group = 1 node (via perm), lane covers dims 4*(lane&15)..+3;
// one uint2 load x 16 lanes = the node's full 128B factor slice. Degree-sorted perm -> the 4 nodes in a
// wave have equal/adjacent degrees -> max(trip) ~ mean(trip), eliminating R6's ~25% divergence waste.
// Per-node edge order unchanged -> bit-identical output.
__global__ __launch_bounds__(256) void k_gather(const int* perm, const int* row_ptr,
                                                const int* csr_src, const float* att_t,
                                                const unsigned short* in16, unsigned short* agg16) {
    int tid = threadIdx.x, f = blockIdx.y;
    int grp = tid >> 4, d4 = tid & 15;
    int n = perm[blockIdx.x * 16 + grp];         // 6250*16 = 100000 exactly, no tail
    int row = row_ptr[n], end = row_ptr[n + 1];
    int total = end - row;
    const unsigned short* inf = in16 + (size_t)f * NN * DD;
    const float* attf = att_t + (size_t)f * EE;
    float a0 = 0.f, a1 = 0.f, a2 = 0.f, a3 = 0.f;
    for (int base = 0; base < total; base += 8) {
        int s[8]; float w[8];
#pragma unroll
        for (int j = 0; j < 8; j++) {
            int e = base + j;
            int idx = row + (e < total ? e : total - 1);   // clamped pad -> cached line, w=0
            s[j] = csr_src[idx];
            float ww = attf[idx];
            w[j] = (e < total) ? ww : 0.f;
        }
        uint2 v[8];
#pragma unroll
        for (int j = 0; j < 8; j++)
            v[j] = *(const uint2*)(inf + (size_t)s[j] * DD + d4 * 4);
#pragma unroll
        for (int j = 0; j < 8; j++) {
            a0 = fmaf(w[j], __uint_as_float(v[j].x << 16), a0);
            a1 = fmaf(w[j], __uint_as_float(v[j].x & 0xffff0000u), a1);
            a2 = fmaf(w[j], __uint_as_float(v[j].y << 16), a2);
            a3 = fmaf(w[j], __uint_as_float(v[j].y & 0xffff0000u), a3);
        }
    }
    ushort4 r;
    r.x = f2bf(a0); r.y = f2bf(a1); r.z = f2bf(a2); r.w = f2bf(a3);
    *(ushort4*)(agg16 + ((size_t)f * NN + n) * DD + d4 * 4) = r;
}

// ---------------------------------------------------------------- fused layer: m = relu(agg@Wrel + out@Wroot + brel); h' = GRU(m, h=out)
// Wave w owns COLUMN-tile nt=w for all 64 rows; weight frags in VGPR (16 loads/wave).
// State arrays deinterleaved [f][n][64] -> staging reads fully contiguous.
__global__ __launch_bounds__(256) void k_layer(int l, const unsigned short* agg16, unsigned short* out16,
                                               const unsigned short* prep, const float* brel,
                                               const float* bih, const float* bhh,
                                               float* feats, int last) {
    int f = blockIdx.y, n0 = blockIdx.x * 64;
    __shared__ unsigned short A1[64 * 72];   // agg tile (pad 64->72)
    __shared__ unsigned short A2[64 * 72];   // out (=h) tile
    __shared__ unsigned short Mt[64 * 72];   // m tile
    int tid = threadIdx.x;
    const unsigned short* aggf = agg16 + (size_t)f * NN * DD;
    const unsigned short* outf = out16 + (size_t)f * NN * DD;
    for (int t = tid; t < 512; t += 256) {   // 64 rows x 8 segs x 8 elems
        int row = t >> 3, seg = t & 7;
        int gn = n0 + row; if (gn >= NN) gn = NN - 1;
        *(uint4*)(A1 + row * 72 + seg * 8) = *(const uint4*)(aggf + (size_t)gn * DD + seg * 8);
        *(uint4*)(A2 + row * 72 + seg * 8) = *(const uint4*)(outf + (size_t)gn * DD + seg * 8);
    }
    __syncthreads();
    int w = tid >> 6, lane = tid & 63, mrow = lane & 15, q = lane >> 4;
    const unsigned short* wrel  = prep + f * PF_STRIDE + OFF_WREL  + l * 4096;
    const unsigned short* wroot = prep + f * PF_STRIDE + OFF_WROOT + l * 4096;

    // phase 1: m for col-tile w, all rows; weights in VGPR
    {
        bf16x8_t wr1[2], wr2[2];
#pragma unroll
        for (int kb = 0; kb < 2; kb++) {
            wr1[kb] = *(const bf16x8_t*)(wrel  + ((w * 2 + kb) * 64 + lane) * 8);
            wr2[kb] = *(const bf16x8_t*)(wroot + ((w * 2 + kb) * 64 + lane) * 8);
        }
        int col = w * 16 + mrow;
        float bias = brel[(f * 3 + l) * DD + col];
#pragma unroll
        for (int mt = 0; mt < 4; mt++) {
            f32x4_t acc = {0.f, 0.f, 0.f, 0.f};
#pragma unroll
            for (int kb = 0; kb < 2; kb++) {
                bf16x8_t a1 = *(const bf16x8_t*)(A1 + (mt * 16 + mrow) * 72 + kb * 32 + q * 8);
                acc = __builtin_amdgcn_mfma_f32_16x16x32_bf16(a1, wr1[kb], acc, 0, 0, 0);
                bf16x8_t a2 = *(const bf16x8_t*)(A2 + (mt * 16 + mrow) * 72 + kb * 32 + q * 8);
                acc = __builtin_amdgcn_mfma_f32_16x16x32_bf16(a2, wr2[kb], acc, 0, 0, 0);
            }
#pragma unroll
            for (int r = 0; r < 4; r++) {
                float mv = acc[r] + bias;
                mv = mv > 0.f ? mv : 0.f;
                Mt[(mt * 16 + q * 4 + r) * 72 + col] = f2bf(mv);
            }
        }
    }
    __syncthreads();

    // phase 2: GRU gates for col-tile w (gate cols w, w+4, w+8 of 192), all rows; 12 weight frags in VGPR
    const unsigned short* wih = prep + f * PF_STRIDE + OFF_WIH;
    const unsigned short* whh = prep + f * PF_STRIDE + OFF_WHH;
    bf16x8_t Br[2], Bz[2], Bn[2], Cr[2], Cz[2], Cn[2];
#pragma unroll
    for (int kb = 0; kb < 2; kb++) {
        Br[kb] = *(const bf16x8_t*)(wih + (((w)     * 2 + kb) * 64 + lane) * 8);
        Bz[kb] = *(const bf16x8_t*)(wih + (((w + 4) * 2 + kb) * 64 + lane) * 8);
        Bn[kb] = *(const bf16x8_t*)(wih + (((w + 8) * 2 + kb) * 64 + lane) * 8);
        Cr[kb] = *(const bf16x8_t*)(whh + (((w)     * 2 + kb) * 64 + lane) * 8);
        Cz[kb] = *(const bf16x8_t*)(whh + (((w + 4) * 2 + kb) * 64 + lane) * 8);
        Cn[kb] = *(const bf16x8_t*)(whh + (((w + 8) * 2 + kb) * 64 + lane) * 8);
    }
    int col = w * 16 + mrow;
    float bi_r = bih[f * 192 + col],        bh_r = bhh[f * 192 + col];
    float bi_z = bih[f * 192 + 64 + col],   bh_z = bhh[f * 192 + 64 + col];
    float bi_n = bih[f * 192 + 128 + col],  bh_n = bhh[f * 192 + 128 + col];
    unsigned short* outwf = out16 + (size_t)f * NN * DD;
#pragma unroll
    for (int mt = 0; mt < 4; mt++) {
        f32x4_t ir = {0.f,0.f,0.f,0.f}, iz = {0.f,0.f,0.f,0.f}, in_ = {0.f,0.f,0.f,0.f};
        f32x4_t hr = {0.f,0.f,0.f,0.f}, hz = {0.f,0.f,0.f,0.f}, hn  = {0.f,0.f,0.f,0.f};
#pragma unroll
        for (int kb = 0; kb < 2; kb++) {
            bf16x8_t am = *(const bf16x8_t*)(Mt + (mt * 16 + mrow) * 72 + kb * 32 + q * 8);
            bf16x8_t ah = *(const bf16x8_t*)(A2 + (mt * 16 + mrow) * 72 + kb * 32 + q * 8);
            ir  = __builtin_amdgcn_mfma_f32_16x16x32_bf16(am, Br[kb], ir, 0, 0, 0);
            iz  = __builtin_amdgcn_mfma_f32_16x16x32_bf16(am, Bz[kb], iz, 0, 0, 0);
            in_ = __builtin_amdgcn_mfma_f32_16x16x32_bf16(am, Bn[kb], in_, 0, 0, 0);
            hr  = __builtin_amdgcn_mfma_f32_16x16x32_bf16(ah, Cr[kb], hr, 0, 0, 0);
            hz  = __builtin_amdgcn_mfma_f32_16x16x32_bf16(ah, Cz[kb], hz, 0, 0, 0);
            hn  = __builtin_amdgcn_mfma_f32_16x16x32_bf16(ah, Cn[kb], hn, 0, 0, 0);
        }
#pragma unroll
        for (int r = 0; r < 4; r++) {
            float rg = sigm(ir[r] + bi_r + hr[r] + bh_r);
            float z  = sigm(iz[r] + bi_z + hz[r] + bh_z);
            float nn = tanh_f(in_[r] + bi_n + rg * (hn[r] + bh_n));
            float h  = b2f(A2[(mt * 16 + q * 4 + r) * 72 + col]);
            float hp = (1.f - z) * nn + z * h;
            int node = n0 + mt * 16 + q * 4 + r;
            if (node < NN) {
                outwf[(size_t)node * DD + col] = f2bf(hp);
                if (last) feats[((size_t)f * NN + node) * DD + col] = hp;
            }
        }
    }
}

// ---------------------------------------------------------------- pool (batch is sorted -> segmented reduce, few atomics)
__global__ __launch_bounds__(256) void k_pool(const float* feats, const int* batch, float* outs) {
    int f = blockIdx.y, w = threadIdx.x >> 6, lane = threadIdx.x & 63;
    int nbase = blockIdx.x * 256 + w * 64;
    if (nbase >= NN) return;
    int g_cur = batch[nbase];
    float acc = 0.f;
    for (int i = 0; i < 64; i++) {
        int n = nbase + i;
        if (n >= NN) break;
        int g = batch[n];
        float v = feats[((size_t)f * NN + n) * DD + lane];
        if (g != g_cur) {
            atomicAdd(&outs[(f * GG + g_cur) * DD + lane], acc);
            acc = v; g_cur = g;
        } else acc += v;
    }
    atomicAdd(&outs[(f * GG + g_cur) * DD + lane], acc);
}
__global__ __launch_bounds__(256) void k_norm(float* outs, const float* counts) {
    int i = blockIdx.x * 256 + threadIdx.x;
    if (i < NFAC * GG * DD) {
        int g = (i >> 6) & (GG - 1);
        outs[i] /= fmaxf(counts[g], 1.f);
    }
}

// ---------------------------------------------------------------- launch
extern "C" void kernel_launch(void* const* d_in, const int* in_sizes, int n_in,
                              void* d_out, int out_size, void* d_ws, size_t ws_size,
                              hipStream_t stream) {
    const float* x    = (const float*)d_in[0];
    const int*   ei   = (const int*)d_in[1];
    const float* att  = (const float*)d_in[2];
    const int*   batch= (const int*)d_in[3];
    const float* linW = (const float*)d_in[4];
    const float* linb = (const float*)d_in[5];
    const float* wrel = (const float*)d_in[6];
    const float* brel = (const float*)d_in[7];
    const float* wroot= (const float*)d_in[8];
    const float* wih  = (const float*)d_in[9];
    const float* whh  = (const float*)d_in[10];
    const float* bih  = (const float*)d_in[11];
    const float* bhh  = (const float*)d_in[12];

    float* outs  = (float*)d_out;                  // [4,128,64]
    float* feats = (float*)d_out + NFAC * GG * DD; // [4,N,64]

    char* p = (char*)d_ws;
    unsigned short* out16 = (unsigned short*)p; p += (size_t)NFAC * NN * DD * 2;
    unsigned short* agg16 = (unsigned short*)p; p += (size_t)NFAC * NN * DD * 2;
    unsigned short* x16   = (unsigned short*)p; p += (size_t)NN * FDIM * 2;
    unsigned short* prep  = (unsigned short*)p; p += (size_t)PREP_TOTAL * 2;
    float* att_t          = (float*)p;          p += (size_t)EE * 16;
    int* csr_src          = (int*)p;            p += (size_t)EE * 4;
    int* deg              = (int*)p;            p += (size_t)NN * 4;
    int* cursor           = (int*)p;            p += (size_t)NN * 4;
    int* row_pos          = (int*)p;            p += (size_t)NN * 4;
    int* row_ptr          = (int*)p;            p += (size_t)(NN + 1) * 4;
    int* perm             = (int*)p;            p += (size_t)NN * 4;
    int* boff             = (int*)p;            p += 512 * 4;
    int* hist             = (int*)p;            p += 256 * 4;
    int* hcur             = (int*)p;            p += 256 * 4;
    float* counts         = (float*)p;          p += 512;

    // interleaved csr_att is only live between k_fill and k_att, both BEFORE the first
    // k_gather write to agg16 -> alias it over agg16's storage
    float* csr_att = (float*)agg16;

    k_init  <<<dim3(391),  dim3(256), 0, stream>>>(deg, cursor, outs, hist);
    k_prep  <<<dim3(4096), dim3(256), 0, stream>>>(x, linW, wrel, wroot, wih, whh, x16, prep);
    k_count <<<dim3(1),    dim3(256), 0, stream>>>(batch, counts);
    k_deg   <<<dim3(6250), dim3(256), 0, stream>>>(ei, deg);
    k_scan1 <<<dim3(391),  dim3(256), 0, stream>>>(deg, row_pos, boff);
    k_scan2 <<<dim3(1),    dim3(512), 0, stream>>>(boff);
    k_rowptr<<<dim3(391),  dim3(256), 0, stream>>>(row_pos, boff, row_ptr);
    k_fill  <<<dim3(6250), dim3(256), 0, stream>>>(ei, att, row_ptr, cursor, csr_src, csr_att);
    k_att   <<<dim3(6250), dim3(256), 0, stream>>>(csr_att, att_t);
    k_hist  <<<dim3(391),  dim3(256), 0, stream>>>(deg, hist);
    k_hscan <<<dim3(1),    dim3(256), 0, stream>>>(hist, hcur);
    k_perm  <<<dim3(391),  dim3(256), 0, stream>>>(deg, hist, hcur, perm);
    k_lin   <<<dim3(1563), dim3(256), 0, stream>>>(x16, prep, linb, out16);
    for (int l = 0; l < NLAY; l++) {
        k_gather<<<dim3(6250, 4), dim3(256), 0, stream>>>(perm, row_ptr, csr_src, att_t, out16, agg16);
        k_layer <<<dim3(1563, 4), dim3(256), 0, stream>>>(l, agg16, out16, prep, brel, bih, bhh,
                                                          feats, (l == NLAY - 1) ? 1 : 0);
    }
    k_pool <<<dim3(391, 4), dim3(256), 0, stream>>>(feats, batch, outs);
    k_norm <<<dim3(128),    dim3(256), 0, stream>>>(outs, counts);
}

// Round 12
// 986.331 us; speedup vs baseline: 1.3197x; 1.3197x over previous
//
#include <hip/hip_runtime.h>

#define NN   100000
#define EE   1600000
#define FDIM 128
#define NFAC 4
#define DD   64
#define NLAY 3
#define GG   128

// node state is deinterleaved per factor: [f][n][64] bf16, one 128B cacheline per (f,n)

// prep weight buffer layout (bf16 elems), per-factor stride:
#define PF_STRIDE 57344
#define OFF_WREL  8192
#define OFF_WROOT 20480
#define OFF_WIH   32768
#define OFF_WHH   45056
#define PREP_TOTAL (NFAC * PF_STRIDE)   // 229376

typedef __bf16 bf16x8_t __attribute__((ext_vector_type(8)));
typedef float  f32x4_t  __attribute__((ext_vector_type(4)));

__device__ __forceinline__ unsigned short f2bf(float x) {
    unsigned u = __float_as_uint(x);
    u += 0x7fffu + ((u >> 16) & 1u);        // round-to-nearest-even
    return (unsigned short)(u >> 16);
}
__device__ __forceinline__ float b2f(unsigned short h) {
    return __uint_as_float(((unsigned)h) << 16);
}
__device__ __forceinline__ float sigm(float x) { return 1.f / (1.f + __expf(-x)); }
__device__ __forceinline__ float tanh_f(float x) {
    float t = __expf(-2.f * fabsf(x));
    float r = (1.f - t) / (1.f + t);
    return x >= 0.f ? r : -r;
}

// ---------------------------------------------------------------- init
__global__ __launch_bounds__(256) void k_init(int* deg, int* cursor, float* outs) {
    int i = blockIdx.x * 256 + threadIdx.x;
    if (i < NN) { deg[i] = 0; cursor[i] = 0; }
    if (i < NFAC * GG * DD) outs[i] = 0.f;
}

// ------------------------------------------------- weight + x bf16 prep
// B-fragment order: for matrix B[k][n]: elem((nt*KB+kb)*64+lane)*8+j = B[kb*32+(lane>>4)*8+j][nt*16+(lane&15)]
__global__ __launch_bounds__(256) void k_prep(const float* x, const float* linW,
                                              const float* wrel, const float* wroot,
                                              const float* wih, const float* whh,
                                              unsigned short* x16, unsigned short* prep) {
    for (int i = blockIdx.x * 256 + threadIdx.x; i < NN * FDIM; i += gridDim.x * 256)
        x16[i] = f2bf(x[i]);
    for (int idx = blockIdx.x * 256 + threadIdx.x; idx < PREP_TOTAL; idx += gridDim.x * 256) {
        int f = idx / PF_STRIDE, r = idx % PF_STRIDE;
        int e, KB, mode, l = 0;
        if (r < OFF_WREL)       { e = r;                 KB = 4; mode = 0; }
        else if (r < OFF_WROOT) { int rr = r - OFF_WREL;  l = rr >> 12; e = rr & 4095; KB = 2; mode = 1; }
        else if (r < OFF_WIH)   { int rr = r - OFF_WROOT; l = rr >> 12; e = rr & 4095; KB = 2; mode = 2; }
        else if (r < OFF_WHH)   { e = r - OFF_WIH;        KB = 2; mode = 3; }
        else                    { e = r - OFF_WHH;        KB = 2; mode = 4; }
        int j = e & 7, lane = (e >> 3) & 63, t = e >> 9;
        int kb = t % KB, nt = t / KB;
        int k = kb * 32 + (lane >> 4) * 8 + j;
        int n = nt * 16 + (lane & 15);
        float v;
        if (mode == 0)      v = linW[(f * FDIM + k) * DD + n];
        else if (mode == 1) v = wrel[((f * 3 + l) * DD + k) * DD + n];
        else if (mode == 2) v = wroot[((f * 3 + l) * DD + k) * DD + n];
        else if (mode == 3) v = wih[(f * 192 + n) * DD + k];   // B = Wih^T
        else                v = whh[(f * 192 + n) * DD + k];
        prep[idx] = f2bf(v);
    }
}

// ---------------------------------------------------------------- counts: batch sorted -> binary search, no atomics
__global__ __launch_bounds__(256) void k_count(const int* batch, float* counts) {
    __shared__ int lb[GG + 1];
    int t = threadIdx.x;
    if (t <= GG) {
        int lo = 0, hi = NN;
        while (lo < hi) { int mid = (lo + hi) >> 1; if (batch[mid] < t) lo = mid + 1; else hi = mid; }
        lb[t] = lo;
    }
    __syncthreads();
    if (t < GG) counts[t] = (float)(lb[t + 1] - lb[t]);
}

// ---------------------------------------------------------------- CSR build
__global__ __launch_bounds__(256) void k_deg(const int* ei, int* deg) {
    int e = blockIdx.x * 256 + threadIdx.x;
    if (e < EE) atomicAdd(&deg[ei[EE + e]], 1);
}
__global__ __launch_bounds__(256) void k_scan1(const int* deg, int* row_pos, int* bsum) {
    __shared__ int lds[256];
    int tid = threadIdx.x, idx = blockIdx.x * 256 + tid;
    int v = (idx < NN) ? deg[idx] : 0;
    lds[tid] = v; __syncthreads();
    for (int s = 1; s < 256; s <<= 1) {
        int t = (tid >= s) ? lds[tid - s] : 0;
        __syncthreads();
        lds[tid] += t;
        __syncthreads();
    }
    if (idx < NN) row_pos[idx] = lds[tid] - v;   // exclusive within block
    if (tid == 255) bsum[blockIdx.x] = lds[255];
}
__global__ __launch_bounds__(512) void k_scan2(int* bsum) {  // 1 block, 512 threads, 391 valid
    __shared__ int lds[512];
    int tid = threadIdx.x;
    int v = (tid < 391) ? bsum[tid] : 0;
    lds[tid] = v; __syncthreads();
    for (int s = 1; s < 512; s <<= 1) {
        int t = (tid >= s) ? lds[tid - s] : 0;
        __syncthreads();
        lds[tid] += t;
        __syncthreads();
    }
    bsum[tid] = lds[tid] - v;                    // exclusive block offsets
}
__global__ __launch_bounds__(256) void k_rowptr(const int* row_pos, const int* boff, int* row_ptr) {
    int i = blockIdx.x * 256 + threadIdx.x;
    if (i < NN) row_ptr[i] = row_pos[i] + boff[i >> 8];
    if (i == 0) row_ptr[NN] = EE;
}
__global__ __launch_bounds__(256) void k_fill(const int* ei, const float* att,
                                              const int* row_ptr, int* cursor,
                                              int* csr_src, float* csr_att) {
    int e = blockIdx.x * 256 + threadIdx.x;
    if (e >= EE) return;
    int d = ei[EE + e];
    int slot = row_ptr[d] + atomicAdd(&cursor[d], 1);
    csr_src[slot] = ei[e];
    *(float4*)(csr_att + (size_t)slot * 4) =
        make_float4(att[e], att[EE + e], att[2 * EE + e], att[3 * EE + e]);
}
// transpose csr_att [E][4] -> att_t [4][E]; coalesced read + 4 coalesced plane writes
__global__ __launch_bounds__(256) void k_att(const float* csr_att, float* att_t) {
    int e = blockIdx.x * 256 + threadIdx.x;
    if (e >= EE) return;
    float4 v = *(const float4*)(csr_att + (size_t)e * 4);
    att_t[e]                  = v.x;
    att_t[(size_t)EE + e]     = v.y;
    att_t[(size_t)2 * EE + e] = v.z;
    att_t[(size_t)3 * EE + e] = v.w;
}

// ---------------------------------------------------------------- lin: wave = factor; b-frags loaded once per nt,
// a-frags preloaded to VGPR; writes deinterleaved out16 [f][n][64]
__global__ __launch_bounds__(256) void k_lin(const unsigned short* x16, const unsigned short* prep,
                                             const float* linb, unsigned short* out16) {
    int n0 = blockIdx.x * 64;
    __shared__ unsigned short xs[64 * 136];      // 128 cols + 8 pad
    int tid = threadIdx.x;
    for (int t = tid; t < 1024; t += 256) {      // 64 rows x 16 segs x 8 elems
        int row = t >> 4, seg = t & 15;
        int gn = n0 + row; if (gn >= NN) gn = NN - 1;
        *(uint4*)(xs + row * 136 + seg * 8) = *(const uint4*)(x16 + (size_t)gn * FDIM + seg * 8);
    }
    __syncthreads();
    int w = tid >> 6, lane = tid & 63, mrow = lane & 15, q = lane >> 4;
    const unsigned short* wp = prep + w * PF_STRIDE;
    bf16x8_t a[4][4];                            // [mt][kb], all row-tiles
#pragma unroll
    for (int mt = 0; mt < 4; mt++)
#pragma unroll
        for (int kb = 0; kb < 4; kb++)
            a[mt][kb] = *(const bf16x8_t*)(xs + (mt * 16 + mrow) * 136 + kb * 32 + q * 8);
#pragma unroll
    for (int nt = 0; nt < 4; nt++) {
        bf16x8_t b[4];
#pragma unroll
        for (int kb = 0; kb < 4; kb++)
            b[kb] = *(const bf16x8_t*)(wp + ((nt * 4 + kb) * 64 + lane) * 8);
        int col = nt * 16 + mrow;
        float bias = linb[w * DD + col];
#pragma unroll
        for (int mt = 0; mt < 4; mt++) {
            f32x4_t acc = {0.f, 0.f, 0.f, 0.f};
#pragma unroll
            for (int kb = 0; kb < 4; kb++)
                acc = __builtin_amdgcn_mfma_f32_16x16x32_bf16(a[mt][kb], b[kb], acc, 0, 0, 0);
#pragma unroll
            for (int r = 0; r < 4; r++) {
                int node = n0 + mt * 16 + q * 4 + r;
                if (node < NN) out16[((size_t)w * NN + node) * DD + col] = f2bf(acc[r] + bias);
            }
        }
    }
}

// ---------------------------------------------------------------- gather, per-factor passes (blockIdx.y = f):
// 16-lane group = 1 node; lane covers dims 4*(lane&15)..+3; one uint2 load x 16 lanes = the node's full
// 128B factor slice (one cacheline). Edge order per dim identical to the interleaved version -> bit-identical.
// Per-pass random working set = 12.8MB (vs 51.2 interleaved) -> ~4x better per-XCD L2 hit rate.
__global__ __launch_bounds__(256) void k_gather(const int* row_ptr, const int* csr_src, const float* att_t,
                                                const unsigned short* in16, unsigned short* agg16) {
    int tid = threadIdx.x, f = blockIdx.y;
    int grp = tid >> 4, d4 = tid & 15;
    int n = blockIdx.x * 16 + grp;               // 6250*16 = 100000 exactly, no tail
    int row = row_ptr[n], end = row_ptr[n + 1];
    int total = end - row;
    const unsigned short* inf = in16 + (size_t)f * NN * DD;
    const float* attf = att_t + (size_t)f * EE;
    float a0 = 0.f, a1 = 0.f, a2 = 0.f, a3 = 0.f;
    for (int base = 0; base < total; base += 8) {
        int s[8]; float w[8];
#pragma unroll
        for (int j = 0; j < 8; j++) {
            int e = base + j;
            int idx = row + (e < total ? e : total - 1);   // clamped pad -> cached line, w=0
            s[j] = csr_src[idx];
            float ww = attf[idx];
            w[j] = (e < total) ? ww : 0.f;
        }
        uint2 v[8];
#pragma unroll
        for (int j = 0; j < 8; j++)
            v[j] = *(const uint2*)(inf + (size_t)s[j] * DD + d4 * 4);
#pragma unroll
        for (int j = 0; j < 8; j++) {
            a0 = fmaf(w[j], __uint_as_float(v[j].x << 16), a0);
            a1 = fmaf(w[j], __uint_as_float(v[j].x & 0xffff0000u), a1);
            a2 = fmaf(w[j], __uint_as_float(v[j].y << 16), a2);
            a3 = fmaf(w[j], __uint_as_float(v[j].y & 0xffff0000u), a3);
        }
    }
    ushort4 r;
    r.x = f2bf(a0); r.y = f2bf(a1); r.z = f2bf(a2); r.w = f2bf(a3);
    *(ushort4*)(agg16 + ((size_t)f * NN + n) * DD + d4 * 4) = r;
}

// ---------------------------------------------------------------- fused layer: m = relu(agg@Wrel + out@Wroot + brel); h' = GRU(m, h=out)
// Wave w owns COLUMN-tile nt=w for all 64 rows; weight frags in VGPR (16 loads/wave).
// State arrays deinterleaved [f][n][64] -> staging reads fully contiguous.
__global__ __launch_bounds__(256) void k_layer(int l, const unsigned short* agg16, unsigned short* out16,
                                               const unsigned short* prep, const float* brel,
                                               const float* bih, const float* bhh,
                                               float* feats, int last) {
    int f = blockIdx.y, n0 = blockIdx.x * 64;
    __shared__ unsigned short A1[64 * 72];   // agg tile (pad 64->72)
    __shared__ unsigned short A2[64 * 72];   // out (=h) tile
    __shared__ unsigned short Mt[64 * 72];   // m tile
    int tid = threadIdx.x;
    const unsigned short* aggf = agg16 + (size_t)f * NN * DD;
    const unsigned short* outf = out16 + (size_t)f * NN * DD;
    for (int t = tid; t < 512; t += 256) {   // 64 rows x 8 segs x 8 elems
        int row = t >> 3, seg = t & 7;
        int gn = n0 + row; if (gn >= NN) gn = NN - 1;
        *(uint4*)(A1 + row * 72 + seg * 8) = *(const uint4*)(aggf + (size_t)gn * DD + seg * 8);
        *(uint4*)(A2 + row * 72 + seg * 8) = *(const uint4*)(outf + (size_t)gn * DD + seg * 8);
    }
    __syncthreads();
    int w = tid >> 6, lane = tid & 63, mrow = lane & 15, q = lane >> 4;
    const unsigned short* wrel  = prep + f * PF_STRIDE + OFF_WREL  + l * 4096;
    const unsigned short* wroot = prep + f * PF_STRIDE + OFF_WROOT + l * 4096;

    // phase 1: m for col-tile w, all rows; weights in VGPR
    {
        bf16x8_t wr1[2], wr2[2];
#pragma unroll
        for (int kb = 0; kb < 2; kb++) {
            wr1[kb] = *(const bf16x8_t*)(wrel  + ((w * 2 + kb) * 64 + lane) * 8);
            wr2[kb] = *(const bf16x8_t*)(wroot + ((w * 2 + kb) * 64 + lane) * 8);
        }
        int col = w * 16 + mrow;
        float bias = brel[(f * 3 + l) * DD + col];
#pragma unroll
        for (int mt = 0; mt < 4; mt++) {
            f32x4_t acc = {0.f, 0.f, 0.f, 0.f};
#pragma unroll
            for (int kb = 0; kb < 2; kb++) {
                bf16x8_t a1 = *(const bf16x8_t*)(A1 + (mt * 16 + mrow) * 72 + kb * 32 + q * 8);
                acc = __builtin_amdgcn_mfma_f32_16x16x32_bf16(a1, wr1[kb], acc, 0, 0, 0);
                bf16x8_t a2 = *(const bf16x8_t*)(A2 + (mt * 16 + mrow) * 72 + kb * 32 + q * 8);
                acc = __builtin_amdgcn_mfma_f32_16x16x32_bf16(a2, wr2[kb], acc, 0, 0, 0);
            }
#pragma unroll
            for (int r = 0; r < 4; r++) {
                float mv = acc[r] + bias;
                mv = mv > 0.f ? mv : 0.f;
                Mt[(mt * 16 + q * 4 + r) * 72 + col] = f2bf(mv);
            }
        }
    }
    __syncthreads();

    // phase 2: GRU gates for col-tile w (gate cols w, w+4, w+8 of 192), all rows; 12 weight frags in VGPR
    const unsigned short* wih = prep + f * PF_STRIDE + OFF_WIH;
    const unsigned short* whh = prep + f * PF_STRIDE + OFF_WHH;
    bf16x8_t Br[2], Bz[2], Bn[2], Cr[2], Cz[2], Cn[2];
#pragma unroll
    for (int kb = 0; kb < 2; kb++) {
        Br[kb] = *(const bf16x8_t*)(wih + (((w)     * 2 + kb) * 64 + lane) * 8);
        Bz[kb] = *(const bf16x8_t*)(wih + (((w + 4) * 2 + kb) * 64 + lane) * 8);
        Bn[kb] = *(const bf16x8_t*)(wih + (((w + 8) * 2 + kb) * 64 + lane) * 8);
        Cr[kb] = *(const bf16x8_t*)(whh + (((w)     * 2 + kb) * 64 + lane) * 8);
        Cz[kb] = *(const bf16x8_t*)(whh + (((w + 4) * 2 + kb) * 64 + lane) * 8);
        Cn[kb] = *(const bf16x8_t*)(whh + (((w + 8) * 2 + kb) * 64 + lane) * 8);
    }
    int col = w * 16 + mrow;
    float bi_r = bih[f * 192 + col],        bh_r = bhh[f * 192 + col];
    float bi_z = bih[f * 192 + 64 + col],   bh_z = bhh[f * 192 + 64 + col];
    float bi_n = bih[f * 192 + 128 + col],  bh_n = bhh[f * 192 + 128 + col];
    unsigned short* outwf = out16 + (size_t)f * NN * DD;
#pragma unroll
    for (int mt = 0; mt < 4; mt++) {
        f32x4_t ir = {0.f,0.f,0.f,0.f}, iz = {0.f,0.f,0.f,0.f}, in_ = {0.f,0.f,0.f,0.f};
        f32x4_t hr = {0.f,0.f,0.f,0.f}, hz = {0.f,0.f,0.f,0.f}, hn  = {0.f,0.f,0.f,0.f};
#pragma unroll
        for (int kb = 0; kb < 2; kb++) {
            bf16x8_t am = *(const bf16x8_t*)(Mt + (mt * 16 + mrow) * 72 + kb * 32 + q * 8);
            bf16x8_t ah = *(const bf16x8_t*)(A2 + (mt * 16 + mrow) * 72 + kb * 32 + q * 8);
            ir  = __builtin_amdgcn_mfma_f32_16x16x32_bf16(am, Br[kb], ir, 0, 0, 0);
            iz  = __builtin_amdgcn_mfma_f32_16x16x32_bf16(am, Bz[kb], iz, 0, 0, 0);
            in_ = __builtin_amdgcn_mfma_f32_16x16x32_bf16(am, Bn[kb], in_, 0, 0, 0);
            hr  = __builtin_amdgcn_mfma_f32_16x16x32_bf16(ah, Cr[kb], hr, 0, 0, 0);
            hz  = __builtin_amdgcn_mfma_f32_16x16x32_bf16(ah, Cz[kb], hz, 0, 0, 0);
            hn  = __builtin_amdgcn_mfma_f32_16x16x32_bf16(ah, Cn[kb], hn, 0, 0, 0);
        }
#pragma unroll
        for (int r = 0; r < 4; r++) {
            float rg = sigm(ir[r] + bi_r + hr[r] + bh_r);
            float z  = sigm(iz[r] + bi_z + hz[r] + bh_z);
            float nn = tanh_f(in_[r] + bi_n + rg * (hn[r] + bh_n));
            float h  = b2f(A2[(mt * 16 + q * 4 + r) * 72 + col]);
            float hp = (1.f - z) * nn + z * h;
            int node = n0 + mt * 16 + q * 4 + r;
            if (node < NN) {
                outwf[(size_t)node * DD + col] = f2bf(hp);
                if (last) feats[((size_t)f * NN + node) * DD + col] = hp;
            }
        }
    }
}

// ---------------------------------------------------------------- pool (batch is sorted -> segmented reduce, few atomics)
__global__ __launch_bounds__(256) void k_pool(const float* feats, const int* batch, float* outs) {
    int f = blockIdx.y, w = threadIdx.x >> 6, lane = threadIdx.x & 63;
    int nbase = blockIdx.x * 256 + w * 64;
    if (nbase >= NN) return;
    int g_cur = batch[nbase];
    float acc = 0.f;
    for (int i = 0; i < 64; i++) {
        int n = nbase + i;
        if (n >= NN) break;
        int g = batch[n];
        float v = feats[((size_t)f * NN + n) * DD + lane];
        if (g != g_cur) {
            atomicAdd(&outs[(f * GG + g_cur) * DD + lane], acc);
            acc = v; g_cur = g;
        } else acc += v;
    }
    atomicAdd(&outs[(f * GG + g_cur) * DD + lane], acc);
}
__global__ __launch_bounds__(256) void k_norm(float* outs, const float* counts) {
    int i = blockIdx.x * 256 + threadIdx.x;
    if (i < NFAC * GG * DD) {
        int g = (i >> 6) & (GG - 1);
        outs[i] /= fmaxf(counts[g], 1.f);
    }
}

// ---------------------------------------------------------------- launch
extern "C" void kernel_launch(void* const* d_in, const int* in_sizes, int n_in,
                              void* d_out, int out_size, void* d_ws, size_t ws_size,
                              hipStream_t stream) {
    const float* x    = (const float*)d_in[0];
    const int*   ei   = (const int*)d_in[1];
    const float* att  = (const float*)d_in[2];
    const int*   batch= (const int*)d_in[3];
    const float* linW = (const float*)d_in[4];
    const float* linb = (const float*)d_in[5];
    const float* wrel = (const float*)d_in[6];
    const float* brel = (const float*)d_in[7];
    const float* wroot= (const float*)d_in[8];
    const float* wih  = (const float*)d_in[9];
    const float* whh  = (const float*)d_in[10];
    const float* bih  = (const float*)d_in[11];
    const float* bhh  = (const float*)d_in[12];

    float* outs  = (float*)d_out;                  // [4,128,64]
    float* feats = (float*)d_out + NFAC * GG * DD; // [4,N,64]

    char* p = (char*)d_ws;
    unsigned short* out16 = (unsigned short*)p; p += (size_t)NFAC * NN * DD * 2;
    unsigned short* agg16 = (unsigned short*)p; p += (size_t)NFAC * NN * DD * 2;
    unsigned short* x16   = (unsigned short*)p; p += (size_t)NN * FDIM * 2;
    unsigned short* prep  = (unsigned short*)p; p += (size_t)PREP_TOTAL * 2;
    float* att_t          = (float*)p;          p += (size_t)EE * 16;
    int* csr_src          = (int*)p;            p += (size_t)EE * 4;
    int* deg              = (int*)p;            p += (size_t)NN * 4;
    int* cursor           = (int*)p;            p += (size_t)NN * 4;
    int* row_pos          = (int*)p;            p += (size_t)NN * 4;
    int* row_ptr          = (int*)p;            p += (size_t)(NN + 1) * 4;
    int* boff             = (int*)p;            p += 512 * 4;
    float* counts         = (float*)p;          p += 512;

    // interleaved csr_att is only live between k_fill and k_att, both BEFORE the first
    // k_gather write to agg16 -> alias it over agg16's storage
    float* csr_att = (float*)agg16;

    k_init  <<<dim3(391),  dim3(256), 0, stream>>>(deg, cursor, outs);
    k_prep  <<<dim3(4096), dim3(256), 0, stream>>>(x, linW, wrel, wroot, wih, whh, x16, prep);
    k_count <<<dim3(1),    dim3(256), 0, stream>>>(batch, counts);
    k_deg   <<<dim3(6250), dim3(256), 0, stream>>>(ei, deg);
    k_scan1 <<<dim3(391),  dim3(256), 0, stream>>>(deg, row_pos, boff);
    k_scan2 <<<dim3(1),    dim3(512), 0, stream>>>(boff);
    k_rowptr<<<dim3(391),  dim3(256), 0, stream>>>(row_pos, boff, row_ptr);
    k_fill  <<<dim3(6250), dim3(256), 0, stream>>>(ei, att, row_ptr, cursor, csr_src, csr_att);
    k_att   <<<dim3(6250), dim3(256), 0, stream>>>(csr_att, att_t);
    k_lin   <<<dim3(1563), dim3(256), 0, stream>>>(x16, prep, linb, out16);
    for (int l = 0; l < NLAY; l++) {
        k_gather<<<dim3(6250, 4), dim3(256), 0, stream>>>(row_ptr, csr_src, att_t, out16, agg16);
        k_layer <<<dim3(1563, 4), dim3(256), 0, stream>>>(l, agg16, out16, prep, brel, bih, bhh,
                                                          feats, (l == NLAY - 1) ? 1 : 0);
    }
    k_pool <<<dim3(391, 4), dim3(256), 0, stream>>>(feats, batch, outs);
    k_norm <<<dim3(128),    dim3(256), 0, stream>>>(outs, counts);
}